// Round 13
// baseline (174.779 us; speedup 1.0000x reference)
//
#include <hip/hip_runtime.h>
#include <cstdint>

using u16 = unsigned short;
using u32 = uint32_t;

typedef __attribute__((ext_vector_type(8))) short bf16x8;   // 8 bf16 = 4 VGPRs
typedef __attribute__((ext_vector_type(4))) float f32x4;    // MFMA accumulator

__device__ __forceinline__ float bf2f(u16 v) { return __uint_as_float(((u32)v) << 16); }
__device__ __forceinline__ u16 f2bf(float f) {
    u32 u = __float_as_uint(f);
    u += 0x7fffu + ((u >> 16) & 1u);   // RNE
    return (u16)(u >> 16);
}

// ---- workspace float offsets ----
#define FLAG_OFF 0
#define WSH_OFF  2097168   // conv weight bf16 fragments: u16[442368] = 221184 f
#define AWF_OFF  2588688   // 4096
#define CBF_OFF  2592784   // 192
#define QBF_OFF  2592976   // 192
#define ABF_OFF  2593168   // 64
#define KRW_OFF  2593232   // 504
#define KRH_OFF  2593736   // 504
#define KB_OFF   2594240   // kbuf bf16: u16[524288]
#define QB_OFF   3118528   // qbuf f32: 524288
#define VB_OFF   3642816   // vbuf bf16 TRANSPOSED [bn][d][i]: u16[524288]
#define AT_OFF   4167104   // 524288
#define WSHQ_OFF 9409984   // qkv weight bf16 fragments: u16[49152] = 24576 f

// ---------------------------------------------------------------------------
// Dtype sniffer (verified; returns 0 on this problem's fp32 inputs).
// ---------------------------------------------------------------------------
__global__ void detect_kernel(const u16* __restrict__ x, int* __restrict__ flag) {
    __shared__ int cnt;
    if (threadIdx.x == 0) cnt = 0;
    __syncthreads();
    int c = 0;
    #pragma unroll
    for (int k = 0; k < 16; k++) {
        u16 v = x[threadIdx.x * 16 + k];
        int e = (v >> 7) & 0xFF;
        c += (e >= 110 && e <= 140) ? 1 : 0;
    }
    atomicAdd(&cnt, c);
    __syncthreads();
    if (threadIdx.x == 0) *flag = (cnt > 3300) ? 1 : 0;   // 1 = bf16 inputs
}

// ---------------------------------------------------------------------------
// Merged prep (VERIFIED R12): wshufC (0..215), wshufQ (216..239), cvt (240..261).
// ---------------------------------------------------------------------------
__global__ __launch_bounds__(256) void prep_kernel(
    const void* __restrict__ cw, const void* __restrict__ qw,
    const void* __restrict__ cb, const void* __restrict__ qb,
    const void* __restrict__ aw, const void* __restrict__ ab,
    const void* __restrict__ kw_, const void* __restrict__ kh_,
    u16* __restrict__ wshC, u16* __restrict__ wshQ,
    float* __restrict__ cbf, float* __restrict__ qbf, float* __restrict__ awf,
    float* __restrict__ abf, float* __restrict__ krw, float* __restrict__ krh,
    const int* __restrict__ flag)
{
    const int blk = blockIdx.x;
    const int fl = *flag;
    if (blk < 240) {
        const void* w; u16* o; int g;
        if (blk < 216) { w = cw; o = wshC; g = blk * 256 + threadIdx.x; }
        else           { w = qw; o = wshQ; g = (blk - 216) * 256 + threadIdx.x; }
        const int kk = g / 768, rem = g % 768;
        const int tile = rem >> 6, lane = rem & 63;
        const int n = tile * 16 + (lane & 15);
        u16 tmp[8];
        #pragma unroll
        for (int j = 0; j < 8; j++) {
            const size_t k = (size_t)(kk * 32 + ((lane >> 4) << 3) + j);
            tmp[j] = fl ? ((const u16*)w)[k * 192 + n]
                        : f2bf(((const float*)w)[k * 192 + n]);
        }
        *(uint4*)(o + (size_t)g * 8) = *(const uint4*)tmp;
    } else {
        const int gid = (blk - 240) * 256 + threadIdx.x;
        const void* src; float* dst; int e;
        if      (gid <  192) { src = cb;  dst = cbf; e = gid; }
        else if (gid <  384) { src = qb;  dst = qbf; e = gid - 192; }
        else if (gid < 4480) { src = aw;  dst = awf; e = gid - 384; }
        else if (gid < 4544) { src = ab;  dst = abf; e = gid - 4480; }
        else if (gid < 5048) { src = kw_; dst = krw; e = gid - 4544; }
        else if (gid < 5552) { src = kh_; dst = krh; e = gid - 5048; }
        else return;
        dst[e] = fl ? bf2f(((const u16*)src)[e]) : ((const float*)src)[e];
    }
}

// ---------------------------------------------------------------------------
// QKV implicit GEMM, bf16 MFMA (VERIFIED body). Epilogue: k -> bf16 [i][d];
// v -> bf16 TRANSPOSED [d][i] (enables direct-global V^T fragments in attn);
// q -> f32, scale 8^-0.5 * log2(e).
// ---------------------------------------------------------------------------
__global__ __launch_bounds__(256) void qkv_mfma_kernel(
    const void* __restrict__ xr, const u16* __restrict__ wsh, const float* __restrict__ qbf_,
    const int* __restrict__ flag,
    u16* __restrict__ kb16, float* __restrict__ qbuf, u16* __restrict__ vt16)
{
    const int coh = blockIdx.x, row = blockIdx.y;
    const int b = row >> 5, h = row & 31;
    const int t = threadIdx.x;
    __shared__ u16 xs[32 * 264];                            // 16896 B
    const int fl = *flag;

    if (fl) {
        const u16* src = (const u16*)xr + (size_t)row * 8192;
        #pragma unroll
        for (int i = 0; i < 4; ++i) {
            const int idx = t + i * 256;
            const int px = idx >> 5, cq = idx & 31;
            *(uint4*)(xs + px * 264 + cq * 8) = *(const uint4*)(src + px * 256 + cq * 8);
        }
    } else {
        const float* src = (const float*)xr + (size_t)row * 8192;
        #pragma unroll
        for (int i = 0; i < 8; ++i) {
            const int idx = t + i * 256;
            const int px = idx >> 6, c4 = idx & 63;
            float4 v = *(const float4*)(src + px * 256 + c4 * 4);
            u32 lo = (u32)f2bf(v.x) | ((u32)f2bf(v.y) << 16);
            u32 hi = (u32)f2bf(v.z) | ((u32)f2bf(v.w) << 16);
            *(uint2*)(xs + px * 264 + c4 * 4) = make_uint2(lo, hi);
        }
    }
    __syncthreads();

    const int lane = t & 63, wave = t >> 6;
    const int Mtile = wave & 1;
    const int tg0 = coh * 6 + (wave >> 1) * 3;
    const int l15 = lane & 15, quad = lane >> 4;

    f32x4 acc[3] = {{0,0,0,0},{0,0,0,0},{0,0,0,0}};

    const u16* ap = xs + (Mtile * 16 + l15) * 264 + quad * 8;
    #pragma unroll
    for (int kk = 0; kk < 8; ++kk) {
        const bf16x8 av = *(const bf16x8*)(ap + kk * 32);
        const u16* wp = wsh + ((size_t)(kk * 12 + tg0) * 64 + lane) * 8;
        const bf16x8 b0 = *(const bf16x8*)(wp);
        const bf16x8 b1 = *(const bf16x8*)(wp + 512);
        const bf16x8 b2 = *(const bf16x8*)(wp + 1024);
        acc[0] = __builtin_amdgcn_mfma_f32_16x16x32_bf16(av, b0, acc[0], 0, 0, 0);
        acc[1] = __builtin_amdgcn_mfma_f32_16x16x32_bf16(av, b1, acc[1], 0, 0, 0);
        acc[2] = __builtin_amdgcn_mfma_f32_16x16x32_bf16(av, b2, acc[2], 0, 0, 0);
    }

    // D layout (verified): col = lane&15, row = quad*4 + reg
    const int px0 = Mtile * 16 + quad * 4;
    #pragma unroll
    for (int ti = 0; ti < 3; ++ti) {
        const int tg = tg0 + ti;
        const int o = tg * 16 + l15;
        const int third = tg >> 2;                          // 0=k,1=q,2=v (wave-uniform)
        const int within = o - third * 64;
        const int n = within >> 3, d = within & 7;
        const float bias = qbf_[o];
        #pragma unroll
        for (int r = 0; r < 4; ++r) {
            const int i = h * 32 + px0 + r;
            const float val = acc[ti][r] + bias;
            if (third == 0)
                kb16[((size_t)(b * 8 + n) * 1024 + i) * 8 + d] = f2bf(val);
            else if (third == 1)
                qbuf[((size_t)(b * 8 + n) * 1024 + i) * 8 + d] = val * 0.51006973050f;
            else   // v transposed: [bn][d][i]
                vt16[((size_t)(b * 8 + n) * 8 + d) * 1024 + i] = f2bf(val);
        }
    }
}

// ---------------------------------------------------------------------------
// Conv 3x3 implicit GEMM, bf16 MFMA. VERIFIED — unchanged.
// ---------------------------------------------------------------------------
__global__ __launch_bounds__(256) void conv_mfma_kernel(
    const void* __restrict__ xr, const u16* __restrict__ wsh, const float* __restrict__ cbf,
    const int* __restrict__ flag, void* __restrict__ out)
{
    const int coh = blockIdx.x, row = blockIdx.y;
    const int b = row >> 5, h = row & 31;
    const int t = threadIdx.x;
    __shared__ u16 xs[3 * 34 * 264];                        // 53856 B
    const int fl = *flag;

    #pragma unroll
    for (int r = 0; r < 3; ++r) {
        const int hh = h + r - 1;
        if (t < 64) {
            const int s = (t >> 5) ? 33 : 0, cq = t & 31;
            *(uint4*)(xs + (r * 34 + s) * 264 + cq * 8) = make_uint4(0, 0, 0, 0);
        }
        const bool ok = (hh >= 0) && (hh < 32);
        const size_t base = ((size_t)((b * 32 + (ok ? hh : 0)) * 32)) * 256;
        if (fl) {
            const u16* src = (const u16*)xr + base;
            #pragma unroll
            for (int i = 0; i < 4; ++i) {
                const int idx = t + i * 256;
                const int px = idx >> 5, cq = idx & 31;
                uint4 v = ok ? *(const uint4*)(src + px * 256 + cq * 8)
                             : make_uint4(0, 0, 0, 0);
                *(uint4*)(xs + (r * 34 + 1 + px) * 264 + cq * 8) = v;
            }
        } else {
            const float* src = (const float*)xr + base;
            #pragma unroll
            for (int i = 0; i < 8; ++i) {
                const int idx = t + i * 256;
                const int px = idx >> 6, c4 = idx & 63;
                float4 v = ok ? *(const float4*)(src + px * 256 + c4 * 4)
                              : make_float4(0.f, 0.f, 0.f, 0.f);
                u32 lo = (u32)f2bf(v.x) | ((u32)f2bf(v.y) << 16);
                u32 hi = (u32)f2bf(v.z) | ((u32)f2bf(v.w) << 16);
                *(uint2*)(xs + (r * 34 + 1 + px) * 264 + c4 * 4) = make_uint2(lo, hi);
            }
        }
    }
    __syncthreads();

    const int lane = t & 63, wave = t >> 6;
    const int Mtile = wave & 1;
    const int tg0 = coh * 6 + (wave >> 1) * 3;
    const int l15 = lane & 15, quad = lane >> 4;

    f32x4 acc[3] = {{0,0,0,0},{0,0,0,0},{0,0,0,0}};

    #pragma unroll
    for (int p = 0; p < 9; ++p) {
        const int kh = p / 3, kw = p - kh * 3;
        const u16* ap = xs + (kh * 34 + kw + Mtile * 16 + l15) * 264 + quad * 8;
        #pragma unroll
        for (int ck = 0; ck < 8; ++ck) {
            const int kk = p * 8 + ck;
            const bf16x8 av = *(const bf16x8*)(ap + ck * 32);
            const u16* wp = wsh + ((size_t)(kk * 12 + tg0) * 64 + lane) * 8;
            const bf16x8 b0 = *(const bf16x8*)(wp);
            const bf16x8 b1 = *(const bf16x8*)(wp + 512);
            const bf16x8 b2 = *(const bf16x8*)(wp + 1024);
            acc[0] = __builtin_amdgcn_mfma_f32_16x16x32_bf16(av, b0, acc[0], 0, 0, 0);
            acc[1] = __builtin_amdgcn_mfma_f32_16x16x32_bf16(av, b1, acc[1], 0, 0, 0);
            acc[2] = __builtin_amdgcn_mfma_f32_16x16x32_bf16(av, b2, acc[2], 0, 0, 0);
        }
    }

    const int px0 = Mtile * 16 + quad * 4;
    #pragma unroll
    for (int ti = 0; ti < 3; ++ti) {
        const int co = (tg0 + ti) * 16 + l15;
        const float bias = cbf[co];
        #pragma unroll
        for (int r = 0; r < 4; ++r) {
            const size_t oidx = ((size_t)row * 32 + px0 + r) * 256 + co;
            const float v = acc[ti][r] + bias;
            if (fl) ((u16*)out)[oidx] = f2bf(v);
            else    ((float*)out)[oidx] = v;
        }
    }
}

// ---------------------------------------------------------------------------
// MFMA flash attention v3. Grid (32,64) = 2048 blocks, 32 q-rows/block.
// 4 waves = 2 M-tiles x 2 chunk-halves (16 chunks/wave -> half serial chain).
// K and V^T fragments DIRECT from global bf16 (no K/V LDS). LDS 16.5 KB ->
// 8 blocks/CU = 100% occupancy. Half-sums merged via small f32 LDS buffer.
// ---------------------------------------------------------------------------
__global__ __launch_bounds__(256) void attn_mfma_kernel(
    const u16* __restrict__ kb16, const float* __restrict__ qbuf, const u16* __restrict__ vt16,
    const float* __restrict__ krw, const float* __restrict__ krh, float* __restrict__ attnbuf)
{
    const int qb = blockIdx.x;           // 0..31 (32 q-rows each)
    const int bn = blockIdx.y;           // 0..63
    const int b = bn >> 3, hn = bn & 7;
    const int t = threadIdx.x;
    const int i0 = qb * 32;

    __shared__ u16   sRW[32 * 40];       // [il][wk] bf16          2560 B
    __shared__ float sRH[32 * 36];       // [hk][il] f32           4608 B
    __shared__ u16   sP [4 * 16 * 56];   // per-wave P, stride 56  7168 B
    __shared__ float sMG[2 * 16 * 17];   // half-sum merge         2176 B (16512 total)

    // ---- rel tables (R11/R12-verified math; il now 0..31) ----
    #pragma unroll
    for (int k4 = 0; k4 < 4; k4++) {
        const int idx = t + k4 * 256;                 // 0..1023
        const int il = idx >> 5, w = idx & 31;
        const int i = i0 + il;
        const float* q = qbuf + ((size_t)bn * 1024 + i) * 8;
        float4 qa = *(const float4*)q, qc = *(const float4*)(q + 4);
        const float* rp = krw + (size_t)(w - (i & 31) + 31) * 8;
        float4 ra = *(const float4*)rp, rc = *(const float4*)(rp + 4);
        sRW[il * 40 + w] = f2bf(qa.x*ra.x + qa.y*ra.y + qa.z*ra.z + qa.w*ra.w
                              + qc.x*rc.x + qc.y*rc.y + qc.z*rc.z + qc.w*rc.w);
        const float* hp = krh + (size_t)(w - (i >> 5) + 31) * 8;
        float4 ha = *(const float4*)hp, hc = *(const float4*)(hp + 4);
        sRH[w * 36 + il] = qa.x*ha.x + qa.y*ha.y + qa.z*ha.z + qa.w*ha.w
                         + qc.x*hc.x + qc.y*hc.y + qc.z*hc.z + qc.w*hc.w;
    }
    __syncthreads();

    const int lane = t & 63, wave = t >> 6;
    const int l15 = lane & 15, quad = lane >> 4;
    const int Mtile = wave >> 1;          // 16-row tile within block
    const int ch0 = (wave & 1) * 16;      // chunk half

    union Frag { u16 a[8]; bf16x8 v; };
    Frag Aq;
    {
        const float* q = qbuf + ((size_t)bn * 1024 + i0 + Mtile * 16 + l15) * 8;
        float4 qa = *(const float4*)q, qc = *(const float4*)(q + 4);
        Aq.a[0] = f2bf(qa.x); Aq.a[1] = f2bf(qa.y); Aq.a[2] = f2bf(qa.z); Aq.a[3] = f2bf(qa.w);
        Aq.a[4] = f2bf(qc.x); Aq.a[5] = f2bf(qc.y); Aq.a[6] = f2bf(qc.z); Aq.a[7] = f2bf(qc.w);
        if (quad != 0) {
            #pragma unroll
            for (int j = 0; j < 8; j++) Aq.a[j] = 0;
        }
    }
    const bf16x8 Arw = *(const bf16x8*)(sRW + (Mtile * 16 + l15) * 40 + quad * 8);

    Frag P0, P1, ONE;
    #pragma unroll
    for (int j = 0; j < 8; j++) { P0.a[j] = 0; P1.a[j] = 0; ONE.a[j] = 0x3F80; }
    {
        const int h0 = l15 - quad * 8;
        if (h0 >= 0 && h0 < 8) P0.a[h0] = 0x3F80;
        const int h1 = 16 + l15 - quad * 8;
        if (h1 >= 0 && h1 < 8) P1.a[h1] = 0x3F80;
    }

    const u16* kg = kb16 + (size_t)bn * 8192;
    const u16* vt = vt16 + (size_t)bn * 8192;
    u16* pb = sP + wave * (16 * 56);
    f32x4 oacc = {0.f, 0.f, 0.f, 0.f};

    for (int c = 0; c < 16; c++) {
        const int chunk = ch0 + c;
        const float4 rh4 = *(const float4*)(sRH + chunk * 36 + Mtile * 16 + quad * 4);
        f32x4 acc0 = {rh4.x, rh4.y, rh4.z, rh4.w};
        f32x4 acc1 = acc0;
        const bf16x8 bk0 = *(const bf16x8*)(kg + (chunk * 32 + l15) * 8);
        const bf16x8 bk1 = *(const bf16x8*)(kg + (chunk * 32 + 16 + l15) * 8);
        acc0 = __builtin_amdgcn_mfma_f32_16x16x32_bf16(Aq.v, bk0, acc0, 0, 0, 0);
        acc0 = __builtin_amdgcn_mfma_f32_16x16x32_bf16(Arw, P0.v, acc0, 0, 0, 0);
        acc1 = __builtin_amdgcn_mfma_f32_16x16x32_bf16(Aq.v, bk1, acc1, 0, 0, 0);
        acc1 = __builtin_amdgcn_mfma_f32_16x16x32_bf16(Arw, P1.v, acc1, 0, 0, 0);
        #pragma unroll
        for (int r = 0; r < 4; r++) {
            const float p0 = exp2f(acc0[r]);   // |s| <~ 60 log2-units: no clamp needed
            const float p1 = exp2f(acc1[r]);
            pb[(quad * 4 + r) * 56 + l15]      = f2bf(p0);
            pb[(quad * 4 + r) * 56 + 16 + l15] = f2bf(p1);
        }
        const bf16x8 Ap = *(const bf16x8*)(pb + l15 * 56 + quad * 8);
        bf16x8 Bv;
        if (l15 < 8) Bv = *(const bf16x8*)(vt + l15 * 1024 + chunk * 32 + quad * 8);
        else         Bv = ONE.v;   // n==8 -> l column
        oacc = __builtin_amdgcn_mfma_f32_16x16x32_bf16(Ap, Bv, oacc, 0, 0, 0);
    }

    // merge the two chunk-half sums per M-tile, then normalize & write
    if (wave & 1) {
        #pragma unroll
        for (int r = 0; r < 4; r++)
            sMG[(Mtile * 16 + quad * 4 + r) * 17 + l15] = oacc[r];
    }
    __syncthreads();
    if (!(wave & 1)) {
        #pragma unroll
        for (int r = 0; r < 4; r++) {
            oacc[r] += sMG[(Mtile * 16 + quad * 4 + r) * 17 + l15];
            const float lr = __shfl(oacc[r], (lane & 48) | 8, 64);
            const float val = oacc[r] / fmaxf(lr, 1e-30f);
            if (l15 < 8) {
                const int i = i0 + Mtile * 16 + quad * 4 + r;
                attnbuf[((size_t)b * 1024 + i) * 64 + hn * 8 + l15] = val;
            }
        }
    }
}

// ---------------------------------------------------------------------------
// Output projection (VERIFIED — unchanged).
// ---------------------------------------------------------------------------
__global__ __launch_bounds__(256) void proj_kernel(
    const float* __restrict__ attnbuf, const float* __restrict__ awf, const float* __restrict__ abf,
    const int* __restrict__ flag, void* __restrict__ out)
{
    const int g = blockIdx.x * 256 + threadIdx.x;
    const int px = g >> 6, o = g & 63;
    const float* ar = attnbuf + (size_t)px * 64;
    float acc = abf[o];
    #pragma unroll 8
    for (int c = 0; c < 64; c++) acc += ar[c] * awf[c * 64 + o];
    if (*flag) ((u16*)out)[(size_t)px * 256 + 192 + o] = f2bf(acc);
    else       ((float*)out)[(size_t)px * 256 + 192 + o] = acc;
}

// ---------------------------------------------------------------------------
extern "C" void kernel_launch(void* const* d_in, const int* in_sizes, int n_in,
                              void* d_out, int out_size, void* d_ws, size_t ws_size,
                              hipStream_t stream)
{
    float* ws = (float*)d_ws;
    int*   flag = (int*)(ws + FLAG_OFF);
    u16*   wsh  = (u16*)(ws + WSH_OFF);
    float* awf  = ws + AWF_OFF;
    float* cbf  = ws + CBF_OFF;
    float* qbf  = ws + QBF_OFF;
    float* abf  = ws + ABF_OFF;
    float* krw  = ws + KRW_OFF;
    float* krh  = ws + KRH_OFF;
    u16*   kb16 = (u16*)(ws + KB_OFF);
    float* qbuf = ws + QB_OFF;
    u16*   vt16 = (u16*)(ws + VB_OFF);
    float* atb  = ws + AT_OFF;
    u16*   wshQ = (u16*)(ws + WSHQ_OFF);

    detect_kernel<<<1, 256, 0, stream>>>((const u16*)d_in[0], flag);

    prep_kernel<<<262, 256, 0, stream>>>(
        d_in[1], d_in[3], d_in[2], d_in[4], d_in[5], d_in[6], d_in[7], d_in[8],
        wsh, wshQ, cbf, qbf, awf, abf, krw, krh, flag);

    qkv_mfma_kernel <<<dim3(2, 256), 256, 0, stream>>>(d_in[0], wshQ, qbf, flag, kb16, qbuf, vt16);
    conv_mfma_kernel<<<dim3(2, 256), 256, 0, stream>>>(d_in[0], wsh, cbf, flag, d_out);
    attn_mfma_kernel<<<dim3(32, 64), 256, 0, stream>>>(kb16, qbuf, vt16, krw, krh, atb);
    proj_kernel     <<<2048,         256, 0, stream>>>(atb, awf, abf, flag, d_out);
}